// Round 20
// baseline (272.093 us; speedup 1.0000x reference)
//
#include <hip/hip_runtime.h>
#include <math.h>

// ---------------------------------------------------------------------------
// Round 19: grid-transpose on conv2/conv3/UV GEMMs. HIP runs blockIdx.x
// fastest; with n on x and m on y, the whole B matrix re-streams once per
// m-tile (conv3: 8.3MB x16 passes, UV: 15.7MB x8, conv2: 16.6MB x4). New
// gemm_kS wrapper feeds gemm_body(bx=blockIdx.y, by=blockIdx.x) so
// concurrent blocks share one B-tile -> B streams ~once. Pure block remap,
// bit-identical math. Everything else = round 18.
// ---------------------------------------------------------------------------

#define NTOT 15376
#define PHALF 2032128   // 3969*512 floats per split-K partial
typedef unsigned short u16;
typedef unsigned long long u64;
typedef __attribute__((ext_vector_type(8))) short bf16x8;
typedef __attribute__((ext_vector_type(4))) float f32x4;

static __device__ __forceinline__ u16 f2bf(float x) {
    union { float f; unsigned u; } v; v.f = x;
    unsigned r = v.u + 0x7FFF + ((v.u >> 16) & 1);
    return (u16)(r >> 16);
}
static __device__ __forceinline__ float bf2f(u16 h) {
    union { unsigned u; float f; } v; v.u = ((unsigned)h) << 16;
    return v.f;
}

// async global->LDS, 16B per lane; LDS dest = wave-uniform base + lane*16
static __device__ __forceinline__ void glds16(const void* g, void* l) {
    __builtin_amdgcn_global_load_lds(
        (const __attribute__((address_space(1))) void*)g,
        (__attribute__((address_space(3))) void*)l,
        16, 0, 0);
}

// ---------------- prep: packs + wc1 + im2col + hbias + anchor packT ---------
// blocks: [0,8832) pack | [8832,8864) wc1 | [8864,9119) im2col |
//         [9119,9631) hbias | [9631,11679) packT anchors
__global__ __launch_bounds__(256) void prep_all(
    const float* __restrict__ s4, const float* __restrict__ s5,
    const float* __restrict__ s6, const float* __restrict__ s7,
    const float* __restrict__ s8, u16* __restrict__ Wpk,
    u16* __restrict__ UVsep,
    const float* __restrict__ c1w, u16* __restrict__ Wc1pk,
    const float* __restrict__ x, u16* __restrict__ x_t,
    const float* __restrict__ W1w, const float* __restrict__ W1b,
    const float* __restrict__ b0, const float* __restrict__ b1,
    const float* __restrict__ b2, const float* __restrict__ b3,
    float* __restrict__ hb,
    const float* __restrict__ a0w, const float* __restrict__ a1w,
    const float* __restrict__ a2w, const float* __restrict__ a3w,
    u16* __restrict__ WpkT)
{
    __shared__ u16 tile[64][65];
    int b = blockIdx.x, t = threadIdx.x;
    if (b < 8832) {
        long i = (long)b * 256 + t;
        if (i >= 2260992L) return;
        if (i < 524288L) {                    // W1: straight cast
            Wpk[8388608L + i] = f2bf(s4[i]);
        } else if (i < 786432L) {             // UV interleave -> UVsep
            long loc = i - 524288L;
            int ic = (int)(loc % 512);
            long row = loc / 512;
            const float* src = (row & 1) ? s6 : s5;
            UVsep[loc] = f2bf(src[(row >> 1) * 512 + ic]);
        } else if (i < 1081344L) {            // conv2 weights, IC=128, NT=9
            long loc = i - 786432L;
            int ic = (int)(loc % 128);
            long r = loc / 128;
            int tt = (int)(r % 9);
            long oc = r / 9;
            Wpk[9175040L + loc] = f2bf(s7[(oc * 128 + ic) * 9 + tt]);
        } else {                              // conv3 weights, IC=256, NT=9
            long loc = i - 1081344L;
            int ic = (int)(loc % 256);
            long r = loc / 256;
            int tt = (int)(r % 9);
            long oc = r / 9;
            Wpk[9469952L + loc] = f2bf(s8[(oc * 256 + ic) * 9 + tt]);
        }
    } else if (b < 8864) {
        int j = (b - 8832) * 256 + t;         // 8192 elems
        if (j < 8192) {
            int oc = j >> 6, k = j & 63;
            Wc1pk[j] = (k < 27) ? f2bf(c1w[oc * 27 + k]) : (u16)0;
        }
    } else if (b < 9119) {
        int sp = (b - 8864) * 256 + t;
        if (sp < 65025) {
            int oy = sp / 255, ox = sp - oy * 255;
            const float* base = x + (long)oy * 2 * 512 + ox * 2;
            u64 pk[16];   // FULL 64-u16 row (upper half zeros) — replay-safe
#pragma unroll
            for (int q = 0; q < 16; ++q) pk[q] = 0;
#pragma unroll
            for (int ic = 0; ic < 3; ++ic)
#pragma unroll
                for (int ky = 0; ky < 3; ++ky)
#pragma unroll
                    for (int kx = 0; kx < 3; ++kx) {
                        int k = ic * 9 + ky * 3 + kx;
                        float v = base[ic * 262144 + ky * 512 + kx];
                        pk[k >> 2] |= (u64)f2bf(v) << ((k & 3) * 16);
                    }
            u64* drow = (u64*)(x_t + (long)sp * 64);
#pragma unroll
            for (int q = 0; q < 16; ++q) drow[q] = pk[q];
        }
    } else if (b < 9631) {
        int w = t >> 6, l = t & 63;
        int idx = (b - 9119) * 4 + w;         // 0..2047
        int a = idx >> 9, m = idx & 511;
        const float* ab = (a == 0) ? b0 : (a == 1) ? b1 : (a == 2) ? b2 : b3;
        float s = 0.f;
        for (int j = l; j < 1024; j += 64)
            s = fmaf(W1w[(long)m * 1024 + j], ab[j], s);
#pragma unroll
        for (int d = 1; d < 64; d <<= 1) s += __shfl_xor(s, d, 64);
        if (l == 0) hb[idx] = s + W1b[m];
    } else {
        // anchor pack+transpose: fp32 OIHW -> WpkT[(a,tap,ic) k][oc] bf16
        int bid = b - 9631;
        int ocb = bid & 15;            // 16 oc-tiles (1024/64)
        int rt  = bid >> 4;            // 0..127 k-row tiles
        const float* src; int kbase, NT;
        if      (rt < 72)  { src = a0w; kbase = 0;    NT = 9; }
        else if (rt < 80)  { src = a1w; kbase = 4608; NT = 1; }
        else if (rt < 104) { src = a2w; kbase = 5120; NT = 3; }
        else               { src = a3w; kbase = 6656; NT = 3; }
        int kloc0 = rt * 64 - kbase;
        int tap = kloc0 >> 9, ic0 = kloc0 & 511;
        int q = t >> 6, ln = t & 63;
#pragma unroll
        for (int i = 0; i < 16; ++i) {
            int ocl = q * 16 + i;
            tile[ocl][ln] = f2bf(src[((long)(ocb * 64 + ocl) * 512 + ic0 + ln) * NT + tap]);
        }
        __syncthreads();
#pragma unroll
        for (int i = 0; i < 16; ++i) {
            int kl = q * 16 + i;
            WpkT[(long)(rt * 64 + kl) * 1024 + ocb * 64 + ln] = tile[ln][kl];
        }
    }
}

// ---------------- split-K combine kernels ------------------------------------
// combA: Hfeat[row 0..3720][c] = relu(P0+P1+hb) bf16  (a0 output)
__global__ __launch_bounds__(256) void combA(
    const float* __restrict__ P, const float* __restrict__ hb,
    u16* __restrict__ Hfeat)
{
    int row = blockIdx.x;
    int oy = row / 61, ox = row - oy * 61;
    long n = (long)(oy * 63 + ox) * 512;
    int c = threadIdx.x * 2;
    float2 p0 = *(const float2*)(P + n + c);
    float2 p1 = *(const float2*)(P + PHALF + n + c);
    float2 bv = *(const float2*)(hb + c);
    float sx = (p0.x + p1.x) + bv.x;
    float sy = (p0.y + p1.y) + bv.y;
    unsigned pk = (unsigned)f2bf(fmaxf(sx, 0.f))
                | ((unsigned)f2bf(fmaxf(sy, 0.f)) << 16);
    *(unsigned*)(Hfeat + (long)row * 512 + c) = pk;
}

// comb3: h3T[65-pad trg][c] = bf16(Q0+Q1+c3b)  (conv3 output)
__global__ __launch_bounds__(256) void comb3(
    const float* __restrict__ P, const float* __restrict__ bias,
    u16* __restrict__ h3T)
{
    int row = blockIdx.x;                  // 0..3968
    int trg = (row / 63) * 65 + row % 63;
    long n = (long)row * 512;
    int c = threadIdx.x * 2;
    float2 q0 = *(const float2*)(P + n + c);
    float2 q1 = *(const float2*)(P + PHALF + n + c);
    float2 b  = *(const float2*)(bias + c);
    unsigned pk = (unsigned)f2bf(q0.x + q1.x + b.x)
                | ((unsigned)f2bf(q0.y + q1.y + b.y) << 16);
    *(unsigned*)(h3T + (long)trg * 512 + c) = pk;
}

// ---------------- the MFMA BT-GEMM body: 64m x 128n, single-buffer -----------
// CMODE: 0 anchors 63->65pad | 1 identity | 2 stride2@255 | 3 stride2@127
// TMODE: 1 single-tap | 4 K-col stepping | 5 conv2 | 6 conv3 | 8 anchors job-table
//        9 single 64-K tile (conv1)
// EMODE: 2 UV head f32 | 4 bias bf16 [gn][M] | 5 anchor mixed | 6 plain bf16
//        7 f32 partial (conv3 split)
template<int CMODE, int EMODE, int TMODE>
static __device__ __forceinline__ void gemm_body(
    int bx, int by, u16* As, u16* Bs,
    const u16* __restrict__ A, const u16* __restrict__ B,
    const float* __restrict__ bias0, const float* __restrict__ bias1,
    const float* __restrict__ bias2, const float* __restrict__ bias3,
    void* __restrict__ Cout, float* __restrict__ Pbuf,
    int M, int N, int RSB, int Ktot, int OH, int OW, int obase)
{
    const int tid = threadIdx.x, w = tid >> 6, l = tid & 63;
    const int wr = w >> 1, wc = w & 1;
    const int sl = l & 7, sh = l >> 3, sx = sl ^ sh;

    int n0, m0;
    bool TW3 = false;
    int part = -1;                 // split-K partial index (a0 jobs)
    int tbase = 0;
    const float* bias = bias0;
    constexpr int ICL2 = (TMODE == 5) ? 1 : (TMODE == 6) ? 2 : (TMODE == 9) ? 0 : 3;
    constexpr int ICK  = 1 << ICL2;
    int ntaps;

    if (TMODE == 8) {
        // XCD-aware swizzle (T1): bid&7 = XCD owns a contiguous 4-n-tile
        // slice of h3T across ALL jobs/m-tiles -> tap re-reads L2-hit.
        int xcd = bx & 7, idx = bx >> 3;       // idx 0..159
        int nt   = xcd * 4 + (idx & 3);        // 0..31 n-tile
        int rest = idx >> 2;                   // 0..39
        int job  = rest >> 3, msub = rest & 7; // job 0..4, m 0..7
        n0 = nt * 128; m0 = msub * 64;
        int anc;
        if      (job == 0) { anc = 0; ntaps = 4; tbase = 0; part = 0; }
        else if (job == 1) { anc = 0; ntaps = 5; tbase = 4; part = 1; }
        else if (job == 2) { anc = 1; ntaps = 1; }
        else if (job == 3) { anc = 2; ntaps = 3; }
        else               { anc = 3; ntaps = 3; }
        TW3 = (anc == 0 || anc == 3);
        A += (anc == 0) ? 0 : (anc == 1) ? 4608 : (anc == 2) ? 5120 : 6656;
        obase = (anc == 0) ? 0 : (anc == 1) ? 3721 : (anc == 2) ? 7690 : 11533;
        OH = (anc == 0 || anc == 2) ? 61 : 63;
        OW = (anc == 0 || anc == 3) ? 61 : 63;
        bias = bias0 + anc * 512;
    } else if (TMODE == 6 && EMODE == 7) {
        // conv3 split-K: half by by>>3
        int half = by >> 3;
        n0 = bx * 128; m0 = (by & 7) * 64;
        ntaps = half ? 5 : 4; tbase = half * 4;
        Cout = (void*)((float*)Cout + (long)half * PHALF);
    } else {
        n0 = bx * 128; m0 = by * 64;
        ntaps = Ktot >> ICL2;
    }
    const long RSA = (TMODE == 8) ? 8192 : (long)Ktot * 64;  // A row stride (u16)
    const long RSB2 = (long)RSB * 2;

    int offB[4], ldsOffB[4], ldsOffA[2];
    const char* aBase[2];
    const char* bBase[4];
#pragma unroll
    for (int j = 0; j < 4; ++j) {
        int r = w * 32 + j * 8 + sh;
        int gn = n0 + r;
        if (CMODE == 0)      { gn = min(gn, 3968);  offB[j] = (gn / 63) * 65 + (gn % 63); }
        else if (CMODE == 1) { offB[j] = min(gn, N - 1); }
        else if (CMODE == 2) { gn = min(gn, 16128); offB[j] = (gn / 127) * 510 + (gn % 127) * 2; }
        else                 { gn = min(gn, 3968);  offB[j] = (gn / 63) * 254 + (gn % 63) * 2; }
        ldsOffB[j] = r * 128;
        bBase[j] = (const char*)B + (long)offB[j] * RSB2 + sx * 16;
    }
#pragma unroll
    for (int j = 0; j < 2; ++j) {
        int r = w * 16 + j * 8 + sh;
        ldsOffA[j] = r * 128;
        aBase[j] = (const char*)A + (long)(m0 + r) * RSA * 2 + sx * 16;
    }

    f32x4 acc[2][4];
#pragma unroll
    for (int a = 0; a < 2; ++a)
#pragma unroll
        for (int b = 0; b < 4; ++b) acc[a][b] = (f32x4){0.f, 0.f, 0.f, 0.f};

    for (int t_ = 0; t_ < ntaps; ++t_) {
        int te = t_ + tbase;                 // effective tap
        long tOffB;
        if (TMODE == 8) {
            int trow_;
            if (TW3) { int q_ = (te * 11) >> 5; trow_ = q_ * 65 + (te - q_ * 3); }
            else       trow_ = te * 65;
            tOffB = (long)trow_ * RSB2;
        } else if (TMODE == 4) {
            tOffB = (long)te * 1024;
        } else if (TMODE == 5) {
            int q_ = (te * 11) >> 5;
            tOffB = (long)(q_ * 255 + (te - q_ * 3)) * RSB2;
        } else if (TMODE == 6) {
            int q_ = (te * 11) >> 5;
            tOffB = (long)(q_ * 127 + (te - q_ * 3)) * RSB2;
        } else {
            tOffB = 0;
        }
        long aOff = (long)te * (ICK * 128);
#pragma unroll
        for (int kb = 0; kb < ICK; ++kb) {   // kb*128: compile-time imm
#pragma unroll
            for (int j = 0; j < 2; ++j)
                glds16(aBase[j] + aOff + kb * 128, (char*)As + ldsOffA[j]);
#pragma unroll
            for (int j = 0; j < 4; ++j)
                glds16(bBase[j] + tOffB + kb * 128, (char*)Bs + ldsOffB[j]);
            __syncthreads();                  // vmcnt(0): tile ready
#pragma unroll
            for (int kk = 0; kk < 2; ++kk) {
                bf16x8 af[2], bfr[4];
#pragma unroll
                for (int f = 0; f < 2; ++f) {
                    int rm = wr * 32 + f * 16 + (l & 15);
                    af[f] = *(const bf16x8*)((const char*)As + rm * 128 +
                               (((kk * 4 + (l >> 4)) ^ (rm & 7)) * 16));
                }
#pragma unroll
                for (int f = 0; f < 4; ++f) {
                    int rn = wc * 64 + f * 16 + (l & 15);
                    bfr[f] = *(const bf16x8*)((const char*)Bs + rn * 128 +
                               (((kk * 4 + (l >> 4)) ^ (rn & 7)) * 16));
                }
#pragma unroll
                for (int fm = 0; fm < 2; ++fm)
#pragma unroll
                    for (int fn = 0; fn < 4; ++fn)
                        acc[fm][fn] = __builtin_amdgcn_mfma_f32_16x16x32_bf16(
                            af[fm], bfr[fn], acc[fm][fn], 0, 0, 0);
            }
            __syncthreads();                  // reads done before next STAGE
        }
    }

    // epilogue
#pragma unroll
    for (int fm = 0; fm < 2; ++fm) {
        int gmb = m0 + wr * 32 + fm * 16 + (l >> 4) * 4;
#pragma unroll
        for (int fn = 0; fn < 4; ++fn) {
            int gn = n0 + wc * 64 + fn * 16 + (l & 15);
            f32x4 v = acc[fm][fn];
            if (EMODE == 2) {
                if (gn < N) {
                    int j0 = gmb >> 1;   // even
                    float u0 = 1.f / (1.f + expf(-(v.x + bias0[j0])));
                    float t0 = tanhf(v.y + bias1[j0]);
                    float u1 = 1.f / (1.f + expf(-(v.z + bias0[j0 + 1])));
                    float t1 = tanhf(v.w + bias1[j0 + 1]);
                    float2 o = { u0 * t0 * bias2[j0], u1 * t1 * bias2[j0 + 1] };
                    *(float2*)((float*)Cout + (long)gn * 256 + j0) = o;
                }
            } else if (EMODE == 4) {
                if (gn < N) {
                    float4 bv = *(const float4*)(bias + gmb);
                    u64 pk = (u64)f2bf(v.x + bv.x)
                           | ((u64)f2bf(v.y + bv.y) << 16)
                           | ((u64)f2bf(v.z + bv.z) << 32)
                           | ((u64)f2bf(v.w + bv.w) << 48);
                    *(u64*)((u16*)Cout + (long)gn * M + gmb) = pk;
                }
            } else if (EMODE == 5) {
                if (TMODE == 8 && part >= 0) {
                    // a0 split-K: raw f32 partial, no bias/relu
                    if (gn < 3969) {
                        float4 o = { v.x, v.y, v.z, v.w };
                        *(float4*)(Pbuf + (long)part * PHALF + (long)gn * 512 + gmb) = o;
                    }
                } else if (gn < 3969) {
                    int oy = gn / 63, ox = gn - oy * 63;
                    if (oy < OH && ox < OW) {
                        int trg = obase + oy * OW + ox;
                        float4 bv = *(const float4*)(bias + gmb);
                        u64 pk = (u64)f2bf(fmaxf(v.x + bv.x, 0.f))
                               | ((u64)f2bf(fmaxf(v.y + bv.y, 0.f)) << 16)
                               | ((u64)f2bf(fmaxf(v.z + bv.z, 0.f)) << 32)
                               | ((u64)f2bf(fmaxf(v.w + bv.w, 0.f)) << 48);
                        *(u64*)((u16*)Cout + (long)trg * M + gmb) = pk;
                    }
                }
            } else if (EMODE == 6) {
                if (gn < N) {
                    u64 pk = (u64)f2bf(v.x)
                           | ((u64)f2bf(v.y) << 16)
                           | ((u64)f2bf(v.z) << 32)
                           | ((u64)f2bf(v.w) << 48);
                    *(u64*)((u16*)Cout + (long)gn * M + gmb) = pk;
                }
            } else {   // EMODE 7: f32 partial [gn][512]
                if (gn < 3969) {
                    float4 o = { v.x, v.y, v.z, v.w };
                    *(float4*)((float*)Cout + (long)gn * 512 + gmb) = o;
                }
            }
        }
    }
}

// ---------------- global GEMM wrappers ---------------------------------------
template<int CMODE, int EMODE, int TMODE>
__global__ __launch_bounds__(256) void gemm_k(
    const u16* __restrict__ A, const u16* __restrict__ B,
    const float* __restrict__ bias0, const float* __restrict__ bias1,
    const float* __restrict__ bias2, const float* __restrict__ bias3,
    void* __restrict__ Cout, float* __restrict__ Pbuf,
    int M, int N, int RSB, int Ktot, int OH, int OW, int obase)
{
    __shared__ u16 As[4096];
    __shared__ u16 Bs[8192];
    gemm_body<CMODE, EMODE, TMODE>(blockIdx.x, blockIdx.y, As, Bs, A, B,
                                   bias0, bias1, bias2, bias3, Cout, Pbuf,
                                   M, N, RSB, Ktot, OH, OW, obase);
}

// swapped wrapper: launch grid (m-tiles, n-tiles); m runs fastest so
// concurrent blocks share one B-tile (B streams ~once instead of x m-tiles).
template<int CMODE, int EMODE, int TMODE>
__global__ __launch_bounds__(256) void gemm_kS(
    const u16* __restrict__ A, const u16* __restrict__ B,
    const float* __restrict__ bias0, const float* __restrict__ bias1,
    const float* __restrict__ bias2, const float* __restrict__ bias3,
    void* __restrict__ Cout, float* __restrict__ Pbuf,
    int M, int N, int RSB, int Ktot, int OH, int OW, int obase)
{
    __shared__ u16 As[4096];
    __shared__ u16 Bs[8192];
    gemm_body<CMODE, EMODE, TMODE>(blockIdx.y, blockIdx.x, As, Bs, A, B,
                                   bias0, bias1, bias2, bias3, Cout, Pbuf,
                                   M, N, RSB, Ktot, OH, OW, obase);
}

// merged conv1-GEMM (blocks [0,1018)) + Wc-GEMM (blocks [1018,1530))
__global__ __launch_bounds__(256) void conv1_wc_k(
    const u16* __restrict__ Wc1pk, const u16* __restrict__ x_t,
    const float* __restrict__ c1b, u16* __restrict__ h1T,
    const u16* __restrict__ WpkT, const u16* __restrict__ W1pk,
    u16* __restrict__ WcAll)
{
    __shared__ u16 As[4096];
    __shared__ u16 Bs[8192];
    int bid = blockIdx.x;
    if (bid < 1018) {
        gemm_body<1, 4, 9>(bid % 509, bid / 509, As, Bs, Wc1pk, x_t,
                           c1b, nullptr, nullptr, nullptr, h1T, nullptr,
                           128, 65025, 64, 1, 0, 0, 0);
    } else {
        int b2 = bid - 1018;
        gemm_body<1, 6, 4>(b2 & 3, b2 >> 2, As, Bs, WpkT, W1pk,
                           nullptr, nullptr, nullptr, nullptr, WcAll, nullptr,
                           8192, 512, 1024, 16, 0, 0, 0);
    }
}

// ---------------- att[n] = sigmoid(Wab + sum_j UVw[n][j]); also zeros rank --
__global__ __launch_bounds__(256) void att_v3(
    const float* __restrict__ UVw, const float* __restrict__ Wab,
    float* __restrict__ att, int* __restrict__ rank, int N)
{
    int t = threadIdx.x, l = t & 63, r = t >> 6;
    int n = blockIdx.x * 4 + r;
    if (t < 4 && blockIdx.x * 4 + t < N) rank[blockIdx.x * 4 + t] = 0;
    if (n >= N) return;
    float4 p = *(const float4*)(UVw + (long)n * 256 + l * 4);
    float s = (p.x + p.y) + (p.z + p.w);
#pragma unroll
    for (int d = 1; d < 64; d <<= 1) s += __shfl_xor(s, d, 64);
    if (l == 0) att[n] = 1.f / (1.f + expf(-(s + Wab[0])));
}

// ---------------- rank: chunk-parallel partial counts (vectorized) ----------
__global__ __launch_bounds__(256) void rank_partial(
    const float* __restrict__ att, int* __restrict__ rank, int N)
{
    __shared__ float sa[1024];
    int n = blockIdx.x * 256 + threadIdx.x;
    int base = blockIdx.y * 1024;
    int cnt = min(1024, N - base);
    for (int t = threadIdx.x; t < cnt; t += 256) sa[t] = att[base + t];
    __syncthreads();
    if (n >= N) return;
    float a = att[n];
    int r = 0;
    const float4* s4 = (const float4*)sa;
    int gq = cnt >> 2;
    for (int q = 0; q < gq; ++q) {
        float4 v = s4[q];
        r += (int)(v.x > a) + (int)(v.y > a) + (int)(v.z > a) + (int)(v.w > a);
    }
    int bnd = n - base;
    bnd = max(0, min(bnd, cnt));
    int bq = bnd >> 2;
    for (int q = 0; q < bq; ++q) {
        float4 v = s4[q];
        r += (int)(v.x == a) + (int)(v.y == a) + (int)(v.z == a) + (int)(v.w == a);
    }
    for (int t = bq << 2; t < bnd; ++t) r += (int)(sa[t] == a);
    atomicAdd(&rank[n], r);
}

// ---------------- fused tail: fc partials + swpc partials -------------------
#define FC_NB 256
#define FC_ROWS 61   // 256*61 = 15616 >= 15376
__device__ __forceinline__ void anchor_coords(int n, float& cx, float& cy,
                                              float& bw, float& bh)
{
    int kh, kw, Wa, loc;
    if (n < 3721)       { kh = 3; kw = 3; Wa = 61; loc = n; }
    else if (n < 7690)  { kh = 1; kw = 1; Wa = 63; loc = n - 3721; }
    else if (n < 11533) { kh = 3; kw = 1; Wa = 63; loc = n - 7690; }
    else                { kh = 1; kw = 3; Wa = 61; loc = n - 11533; }
    int iy = loc / Wa, ix = loc - iy * Wa;
    cx = (ix + kw * 0.5f) * (1.f / 63.f);
    cy = (iy + kh * 0.5f) * (1.f / 63.f);
    bw = kw * (1.f / 63.f);
    bh = kh * (1.f / 63.f);
}

__global__ __launch_bounds__(256) void tail_part(
    const u16* __restrict__ Hfeat, const float* __restrict__ att,
    const int* __restrict__ rank, float* __restrict__ fcp,
    float* __restrict__ prt, int N)
{
    __shared__ float red[4][50];
    int t = threadIdx.x;
    if (blockIdx.x < FC_NB) {
        int b = blockIdx.x;
        int l = t & 63, r = t >> 6;
        float acc[10][8];
#pragma unroll
        for (int k = 0; k < 10; ++k)
#pragma unroll
            for (int e = 0; e < 8; ++e) acc[k][e] = 0.f;
        int n0 = b * FC_ROWS;
        for (int it = 0; it < 16; ++it) {
            int nl = it * 4 + r;
            int n = n0 + nl;
            if (nl >= FC_ROWS || n >= N) break;   // wave-uniform exit
            float a = att[n];
            int c = (rank[n] * 10) / N;
            bf16x8 h8 = *(const bf16x8*)(Hfeat + (long)n * 512 + l * 8);
            float hf[8];
#pragma unroll
            for (int e = 0; e < 8; ++e) hf[e] = bf2f((u16)h8[e]);
#pragma unroll
            for (int k = 0; k < 10; ++k) {
                float sel = (c == k) ? a : 0.f;
#pragma unroll
                for (int e = 0; e < 8; ++e)
                    acc[k][e] = fmaf(sel, hf[e], acc[k][e]);
            }
        }
        float* dst = fcp + (long)b * 5120 + l * 8;
#pragma unroll
        for (int k = 0; k < 10; ++k)
#pragma unroll
            for (int e = 0; e < 8; ++e) dst[k * 512 + e] = acc[k][e];
    } else {
        int b = blockIdx.x - FC_NB;
        int n = b * 256 + t;
        int l = t & 63, w = t >> 6;
        float a = 0.f, cx = 0.f, cy = 0.f, bw = 0.f, bh = 0.f;
        int c = -1;
        if (n < N) {
            a = att[n]; c = (rank[n] * 10) / N;
            anchor_coords(n, cx, cy, bw, bh);
        }
#pragma unroll
        for (int k = 0; k < 10; ++k) {
            float sel = (c == k) ? a : 0.f;
            float v[5] = {sel, sel * cx, sel * cy, sel * bw, sel * bh};
#pragma unroll
            for (int d = 0; d < 5; ++d) {
                float x = v[d];
#pragma unroll
                for (int s = 1; s < 64; s <<= 1) x += __shfl_xor(x, s, 64);
                if (l == 0) red[w][k * 5 + d] = x;
            }
        }
        __syncthreads();
        if (t < 50) prt[b * 50 + t] = red[0][t] + red[1][t] + red[2][t] + red[3][t];
    }
}

// fc_raw[i] = sum_b fcp[b][i], fixed order (deterministic, coalesced)
__global__ __launch_bounds__(256) void fc_sum(
    const float* __restrict__ fcp, float* __restrict__ fc_raw)
{
    int i = blockIdx.x * 256 + threadIdx.x;
    if (i >= 5120) return;
    float s = 0.f;
    for (int b = 0; b < FC_NB; ++b) s += fcp[(long)b * 5120 + i];
    fc_raw[i] = s;
}

// ---------------- head (includes swpc final sum) ----------------------------
__global__ __launch_bounds__(512) void final_kernel(
    const float* __restrict__ fc_raw, const float* __restrict__ prt,
    const float* __restrict__ cluster_w, const float* __restrict__ cluster_b,
    const float* __restrict__ cls_w, const float* __restrict__ cls_b,
    float* __restrict__ out)
{
    __shared__ float red[512];
    __shared__ float swpc[50];   // k*5+d: d=0 sw, d=1..4 pc
    int t = threadIdx.x;
    if (t < 50) {
        float s = 0.f;
        for (int b = 0; b < 61; ++b) s += prt[b * 50 + t];
        swpc[t] = s;
    }
    __syncthreads();
    float fcn[10];
#pragma unroll
    for (int k = 0; k < 10; ++k)
        fcn[k] = fc_raw[k * 512 + t] / (swpc[k * 5] + 1e-8f);
    float cw = cluster_w[t];
    float sc[10];
#pragma unroll
    for (int k = 0; k < 10; ++k) {
        red[t] = fcn[k] * cw;
        __syncthreads();
        for (int s = 256; s > 0; s >>= 1) {
            if (t < s) red[t] += red[t + s];
            __syncthreads();
        }
        sc[k] = red[0] + cluster_b[0];
        __syncthreads();
    }
    float mx = sc[0];
#pragma unroll
    for (int k = 1; k < 10; ++k) mx = fmaxf(mx, sc[k]);
    float se = 0.f;
#pragma unroll
    for (int k = 0; k < 10; ++k) { sc[k] = expf(sc[k] - mx); se += sc[k]; }
    float inv = 1.f / se;
#pragma unroll
    for (int k = 0; k < 10; ++k) sc[k] *= inv;
    float fm = 0.f;
#pragma unroll
    for (int k = 0; k < 10; ++k) fm = fmaf(sc[k], fcn[k], fm);
    float lg[10];
#pragma unroll
    for (int c = 0; c < 10; ++c) {
        red[t] = fm * cls_w[c * 512 + t];
        __syncthreads();
        for (int s = 256; s > 0; s >>= 1) {
            if (t < s) red[t] += red[t + s];
            __syncthreads();
        }
        lg[c] = red[0] + cls_b[c];
        __syncthreads();
    }
    float mx2 = lg[0];
#pragma unroll
    for (int c = 1; c < 10; ++c) mx2 = fmaxf(mx2, lg[c]);
    float se2 = 0.f;
#pragma unroll
    for (int c = 0; c < 10; ++c) { lg[c] = expf(lg[c] - mx2); se2 += lg[c]; }
    float inv2 = 1.f / se2;
    if (t < 10) out[t] = lg[t] * inv2;
    if (t >= 10 && t < 20) out[t] = sc[t - 10];
    if (t >= 20 && t < 60) {
        int i = t - 20;
        int k = i >> 2, d = i & 3;
        out[t] = swpc[k * 5 + 1 + d] / (swpc[k * 5] + 1e-8f);
    }
}

// ---------------------------------------------------------------------------
extern "C" void kernel_launch(void* const* d_in, const int* in_sizes, int n_in,
                              void* d_out, int out_size, void* d_ws, size_t ws_size,
                              hipStream_t stream)
{
    const float* x    = (const float*)d_in[0];
    const float* c1w  = (const float*)d_in[1];   const float* c1b = (const float*)d_in[2];
    const float* c2w  = (const float*)d_in[3];   const float* c2b = (const float*)d_in[4];
    const float* c3w  = (const float*)d_in[5];   const float* c3b = (const float*)d_in[6];
    const float* a0w  = (const float*)d_in[7];   const float* a0b = (const float*)d_in[8];
    const float* a1w  = (const float*)d_in[9];   const float* a1b = (const float*)d_in[10];
    const float* a2w  = (const float*)d_in[11];  const float* a2b = (const float*)d_in[12];
    const float* a3w  = (const float*)d_in[13];  const float* a3b = (const float*)d_in[14];
    const float* W1w  = (const float*)d_in[15];  const float* W1b = (const float*)d_in[16];
    const float* Uw   = (const float*)d_in[17];  const float* Ub  = (const float*)d_in[18];
    const float* Vw   = (const float*)d_in[19];  const float* Vb  = (const float*)d_in[20];
    const float* Waw  = (const float*)d_in[21];  const float* Wab = (const float*)d_in[22];
    const float* clw  = (const float*)d_in[23];  const float* clb = (const float*)d_in[24];
    const float* clsw = (const float*)d_in[25];  const float* clsb= (const float*)d_in[26];
    float* out = (float*)d_out;

    // ---- workspace layout (float units) -----------------------------------
    float* ws = (float*)d_ws;
    u16*   Hfeat= (u16*)ws;                     // 15376*512 u16    @0
    u16*   h1T  = (u16*)(ws + 3936256);         // 65025*128 u16
    u16*   h2T  = (u16*)(ws + 8097856);         // 16129*256 u16
    u16*   h3T  = (u16*)(ws + 10162368);        // 4225*512 u16
    float* UVw  = ws + 11243968;                // 15376*256 f32
    u16*   x_t  = (u16*)(ws + 11243968);        //   65025*64 u16 (overlay, dead b4 UVw)
    u16*   Wpk  = (u16*)(ws + 15180224);        // W1pk/Wc2pk/Wc3pk
    float* P    = ws + 15180224;                //   split-K partials 2*PHALF (overlay;
                                                //   [15.18M,19.24M) < W1pk 19.37M)
    u16*   WpkT = (u16*)(ws + 20505024);        // 8192*1024 u16 (dead after Wc GEMM)
    u16*   WcAll= (u16*)(ws + 24699328);        // 512*8192 u16
    float* hb   = ws + 26796480;                // 2048
    float* att  = ws + 26798528;                // 15,376
    int*   rank = (int*)(ws + 26813904);        // 15,376
    float* fcr  = ws + 26829280;                // 5,120
    float* fcp  = ws + 26834400;                // 256*5120
    float* prt  = ws + 28145120;                // 61*50
    u16*   Wc1pk= (u16*)(ws + 28148224);        // 128*64 u16
    u16*   UVpk = (u16*)(ws + 28152320);        // 512*512 u16 (dedicated, safe)
    // total ~28.29M floats ~= 113.2 MB

    u16* W1pk  = Wpk + 8388608;
    u16* Wc2pk = Wpk + 9175040;
    u16* Wc3pk = Wpk + 9469952;

    dim3 blk(256);
    const float* nul = nullptr;
    float* fnul = nullptr;

    // ---- prep (input-only deps; includes anchor packT) ---------------------
    prep_all<<<dim3(11679), blk, 0, stream>>>(W1w, Uw, Vw, c2w, c3w, Wpk, UVpk,
                                              c1w, Wc1pk, x, x_t, W1w, W1b,
                                              a0b, a1b, a2b, a3b, hb,
                                              a0w, a1w, a2w, a3w, WpkT);

    // ---- conv1 GEMM + Wc GEMM, one dispatch (independent) ------------------
    conv1_wc_k<<<dim3(1530), blk, 0, stream>>>(Wc1pk, x_t, c1b, h1T,
                                               WpkT, W1pk, WcAll);

    // ---- backbone (grid-transposed: m fastest, B streams once) -------------
    gemm_kS<2,4,5><<<dim3(4, 127), blk, 0, stream>>>(Wc2pk, h1T, c2b, nul, nul, nul, h2T, fnul, 256, 16129, 128, 18, 0, 0, 0);
    gemm_kS<3,7,6><<<dim3(16, 32), blk, 0, stream>>>(Wc3pk, h2T, nul, nul, nul, nul, P, fnul, 512, 3969, 256, 36, 0, 0, 0);
    comb3<<<dim3(3969), blk, 0, stream>>>(P, c3b, h3T);

    // ---- fused anchor+W1 GEMMs (job table, a0 2-way split-K, XCD swizzle) --
    gemm_k<0,5,8><<<dim3(1280), blk, 0, stream>>>(WcAll, h3T, hb, nul, nul, nul, Hfeat, P, 512, 3969, 512, 0, 0, 0, 0);
    combA<<<dim3(3721), blk, 0, stream>>>(P, hb, Hfeat);

    // ---- UV GEMM (grid-transposed): UVw[n][256], f32 ------------------------
    gemm_kS<1,2,1><<<dim3(8, 121), blk, 0, stream>>>(UVpk, Hfeat, Ub, Vb, Waw, nul, UVw, fnul, 512, NTOT, 512, 8, 0, 0, 0);

    // ---- attention (+rank zero), rank, reductions, head --------------------
    att_v3<<<dim3(3844), blk, 0, stream>>>(UVw, Wab, att, rank, NTOT);
    rank_partial<<<dim3(61, 16), blk, 0, stream>>>(att, rank, NTOT);
    tail_part<<<dim3(FC_NB + 61), blk, 0, stream>>>(Hfeat, att, rank, fcp, prt, NTOT);
    fc_sum<<<dim3(20), blk, 0, stream>>>(fcp, fcr);
    final_kernel<<<dim3(1), dim3(512), 0, stream>>>(fcr, prt, clw, clb, clsw, clsb, out);
}

// Round 21
// 267.101 us; speedup vs baseline: 1.0187x; 1.0187x over previous
//
#include <hip/hip_runtime.h>
#include <math.h>

// ---------------------------------------------------------------------------
// Round 20: revert round-19 grid-transpose (regressed 267.5 -> 272.1 us; the
// CP round-robins blocks across XCDs regardless of index order, and with m
// fastest the A weights re-stream instead). This is round 18 verbatim — the
// best measured configuration (267.5 us):
//  - bf16 MFMA everywhere (conv1 via im2col), algebraic W1-fusion (Wc=W1@A),
//  - a0 2-way split-K + XCD swizzle, conv3 2-way split-K,
//  - merged conv1+Wc dispatch, mega-prep, fused tail, vectorized rank.
// ---------------------------------------------------------------------------

#define NTOT 15376
#define PHALF 2032128   // 3969*512 floats per split-K partial
typedef unsigned short u16;
typedef unsigned long long u64;
typedef __attribute__((ext_vector_type(8))) short bf16x8;
typedef __attribute__((ext_vector_type(4))) float f32x4;

static __device__ __forceinline__ u16 f2bf(float x) {
    union { float f; unsigned u; } v; v.f = x;
    unsigned r = v.u + 0x7FFF + ((v.u >> 16) & 1);
    return (u16)(r >> 16);
}
static __device__ __forceinline__ float bf2f(u16 h) {
    union { unsigned u; float f; } v; v.u = ((unsigned)h) << 16;
    return v.f;
}

// async global->LDS, 16B per lane; LDS dest = wave-uniform base + lane*16
static __device__ __forceinline__ void glds16(const void* g, void* l) {
    __builtin_amdgcn_global_load_lds(
        (const __attribute__((address_space(1))) void*)g,
        (__attribute__((address_space(3))) void*)l,
        16, 0, 0);
}

// ---------------- prep: packs + wc1 + im2col + hbias + anchor packT ---------
// blocks: [0,8832) pack | [8832,8864) wc1 | [8864,9119) im2col |
//         [9119,9631) hbias | [9631,11679) packT anchors
__global__ __launch_bounds__(256) void prep_all(
    const float* __restrict__ s4, const float* __restrict__ s5,
    const float* __restrict__ s6, const float* __restrict__ s7,
    const float* __restrict__ s8, u16* __restrict__ Wpk,
    u16* __restrict__ UVsep,
    const float* __restrict__ c1w, u16* __restrict__ Wc1pk,
    const float* __restrict__ x, u16* __restrict__ x_t,
    const float* __restrict__ W1w, const float* __restrict__ W1b,
    const float* __restrict__ b0, const float* __restrict__ b1,
    const float* __restrict__ b2, const float* __restrict__ b3,
    float* __restrict__ hb,
    const float* __restrict__ a0w, const float* __restrict__ a1w,
    const float* __restrict__ a2w, const float* __restrict__ a3w,
    u16* __restrict__ WpkT)
{
    __shared__ u16 tile[64][65];
    int b = blockIdx.x, t = threadIdx.x;
    if (b < 8832) {
        long i = (long)b * 256 + t;
        if (i >= 2260992L) return;
        if (i < 524288L) {                    // W1: straight cast
            Wpk[8388608L + i] = f2bf(s4[i]);
        } else if (i < 786432L) {             // UV interleave -> UVsep
            long loc = i - 524288L;
            int ic = (int)(loc % 512);
            long row = loc / 512;
            const float* src = (row & 1) ? s6 : s5;
            UVsep[loc] = f2bf(src[(row >> 1) * 512 + ic]);
        } else if (i < 1081344L) {            // conv2 weights, IC=128, NT=9
            long loc = i - 786432L;
            int ic = (int)(loc % 128);
            long r = loc / 128;
            int tt = (int)(r % 9);
            long oc = r / 9;
            Wpk[9175040L + loc] = f2bf(s7[(oc * 128 + ic) * 9 + tt]);
        } else {                              // conv3 weights, IC=256, NT=9
            long loc = i - 1081344L;
            int ic = (int)(loc % 256);
            long r = loc / 256;
            int tt = (int)(r % 9);
            long oc = r / 9;
            Wpk[9469952L + loc] = f2bf(s8[(oc * 256 + ic) * 9 + tt]);
        }
    } else if (b < 8864) {
        int j = (b - 8832) * 256 + t;         // 8192 elems
        if (j < 8192) {
            int oc = j >> 6, k = j & 63;
            Wc1pk[j] = (k < 27) ? f2bf(c1w[oc * 27 + k]) : (u16)0;
        }
    } else if (b < 9119) {
        int sp = (b - 8864) * 256 + t;
        if (sp < 65025) {
            int oy = sp / 255, ox = sp - oy * 255;
            const float* base = x + (long)oy * 2 * 512 + ox * 2;
            u64 pk[16];   // FULL 64-u16 row (upper half zeros) — replay-safe
#pragma unroll
            for (int q = 0; q < 16; ++q) pk[q] = 0;
#pragma unroll
            for (int ic = 0; ic < 3; ++ic)
#pragma unroll
                for (int ky = 0; ky < 3; ++ky)
#pragma unroll
                    for (int kx = 0; kx < 3; ++kx) {
                        int k = ic * 9 + ky * 3 + kx;
                        float v = base[ic * 262144 + ky * 512 + kx];
                        pk[k >> 2] |= (u64)f2bf(v) << ((k & 3) * 16);
                    }
            u64* drow = (u64*)(x_t + (long)sp * 64);
#pragma unroll
            for (int q = 0; q < 16; ++q) drow[q] = pk[q];
        }
    } else if (b < 9631) {
        int w = t >> 6, l = t & 63;
        int idx = (b - 9119) * 4 + w;         // 0..2047
        int a = idx >> 9, m = idx & 511;
        const float* ab = (a == 0) ? b0 : (a == 1) ? b1 : (a == 2) ? b2 : b3;
        float s = 0.f;
        for (int j = l; j < 1024; j += 64)
            s = fmaf(W1w[(long)m * 1024 + j], ab[j], s);
#pragma unroll
        for (int d = 1; d < 64; d <<= 1) s += __shfl_xor(s, d, 64);
        if (l == 0) hb[idx] = s + W1b[m];
    } else {
        // anchor pack+transpose: fp32 OIHW -> WpkT[(a,tap,ic) k][oc] bf16
        int bid = b - 9631;
        int ocb = bid & 15;            // 16 oc-tiles (1024/64)
        int rt  = bid >> 4;            // 0..127 k-row tiles
        const float* src; int kbase, NT;
        if      (rt < 72)  { src = a0w; kbase = 0;    NT = 9; }
        else if (rt < 80)  { src = a1w; kbase = 4608; NT = 1; }
        else if (rt < 104) { src = a2w; kbase = 5120; NT = 3; }
        else               { src = a3w; kbase = 6656; NT = 3; }
        int kloc0 = rt * 64 - kbase;
        int tap = kloc0 >> 9, ic0 = kloc0 & 511;
        int q = t >> 6, ln = t & 63;
#pragma unroll
        for (int i = 0; i < 16; ++i) {
            int ocl = q * 16 + i;
            tile[ocl][ln] = f2bf(src[((long)(ocb * 64 + ocl) * 512 + ic0 + ln) * NT + tap]);
        }
        __syncthreads();
#pragma unroll
        for (int i = 0; i < 16; ++i) {
            int kl = q * 16 + i;
            WpkT[(long)(rt * 64 + kl) * 1024 + ocb * 64 + ln] = tile[ln][kl];
        }
    }
}

// ---------------- split-K combine kernels ------------------------------------
// combA: Hfeat[row 0..3720][c] = relu(P0+P1+hb) bf16  (a0 output)
__global__ __launch_bounds__(256) void combA(
    const float* __restrict__ P, const float* __restrict__ hb,
    u16* __restrict__ Hfeat)
{
    int row = blockIdx.x;
    int oy = row / 61, ox = row - oy * 61;
    long n = (long)(oy * 63 + ox) * 512;
    int c = threadIdx.x * 2;
    float2 p0 = *(const float2*)(P + n + c);
    float2 p1 = *(const float2*)(P + PHALF + n + c);
    float2 bv = *(const float2*)(hb + c);
    float sx = (p0.x + p1.x) + bv.x;
    float sy = (p0.y + p1.y) + bv.y;
    unsigned pk = (unsigned)f2bf(fmaxf(sx, 0.f))
                | ((unsigned)f2bf(fmaxf(sy, 0.f)) << 16);
    *(unsigned*)(Hfeat + (long)row * 512 + c) = pk;
}

// comb3: h3T[65-pad trg][c] = bf16(Q0+Q1+c3b)  (conv3 output)
__global__ __launch_bounds__(256) void comb3(
    const float* __restrict__ P, const float* __restrict__ bias,
    u16* __restrict__ h3T)
{
    int row = blockIdx.x;                  // 0..3968
    int trg = (row / 63) * 65 + row % 63;
    long n = (long)row * 512;
    int c = threadIdx.x * 2;
    float2 q0 = *(const float2*)(P + n + c);
    float2 q1 = *(const float2*)(P + PHALF + n + c);
    float2 b  = *(const float2*)(bias + c);
    unsigned pk = (unsigned)f2bf(q0.x + q1.x + b.x)
                | ((unsigned)f2bf(q0.y + q1.y + b.y) << 16);
    *(unsigned*)(h3T + (long)trg * 512 + c) = pk;
}

// ---------------- the MFMA BT-GEMM body: 64m x 128n, single-buffer -----------
// CMODE: 0 anchors 63->65pad | 1 identity | 2 stride2@255 | 3 stride2@127
// TMODE: 1 single-tap | 4 K-col stepping | 5 conv2 | 6 conv3 | 8 anchors job-table
//        9 single 64-K tile (conv1)
// EMODE: 2 UV head f32 | 4 bias bf16 [gn][M] | 5 anchor mixed | 6 plain bf16
//        7 f32 partial (conv3 split)
template<int CMODE, int EMODE, int TMODE>
static __device__ __forceinline__ void gemm_body(
    int bx, int by, u16* As, u16* Bs,
    const u16* __restrict__ A, const u16* __restrict__ B,
    const float* __restrict__ bias0, const float* __restrict__ bias1,
    const float* __restrict__ bias2, const float* __restrict__ bias3,
    void* __restrict__ Cout, float* __restrict__ Pbuf,
    int M, int N, int RSB, int Ktot, int OH, int OW, int obase)
{
    const int tid = threadIdx.x, w = tid >> 6, l = tid & 63;
    const int wr = w >> 1, wc = w & 1;
    const int sl = l & 7, sh = l >> 3, sx = sl ^ sh;

    int n0, m0;
    bool TW3 = false;
    int part = -1;                 // split-K partial index (a0 jobs)
    int tbase = 0;
    const float* bias = bias0;
    constexpr int ICL2 = (TMODE == 5) ? 1 : (TMODE == 6) ? 2 : (TMODE == 9) ? 0 : 3;
    constexpr int ICK  = 1 << ICL2;
    int ntaps;

    if (TMODE == 8) {
        // XCD-aware swizzle (T1): bid&7 = XCD owns a contiguous 4-n-tile
        // slice of h3T across ALL jobs/m-tiles -> tap re-reads L2-hit.
        int xcd = bx & 7, idx = bx >> 3;       // idx 0..159
        int nt   = xcd * 4 + (idx & 3);        // 0..31 n-tile
        int rest = idx >> 2;                   // 0..39
        int job  = rest >> 3, msub = rest & 7; // job 0..4, m 0..7
        n0 = nt * 128; m0 = msub * 64;
        int anc;
        if      (job == 0) { anc = 0; ntaps = 4; tbase = 0; part = 0; }
        else if (job == 1) { anc = 0; ntaps = 5; tbase = 4; part = 1; }
        else if (job == 2) { anc = 1; ntaps = 1; }
        else if (job == 3) { anc = 2; ntaps = 3; }
        else               { anc = 3; ntaps = 3; }
        TW3 = (anc == 0 || anc == 3);
        A += (anc == 0) ? 0 : (anc == 1) ? 4608 : (anc == 2) ? 5120 : 6656;
        obase = (anc == 0) ? 0 : (anc == 1) ? 3721 : (anc == 2) ? 7690 : 11533;
        OH = (anc == 0 || anc == 2) ? 61 : 63;
        OW = (anc == 0 || anc == 3) ? 61 : 63;
        bias = bias0 + anc * 512;
    } else if (TMODE == 6 && EMODE == 7) {
        // conv3 split-K: half by by>>3
        int half = by >> 3;
        n0 = bx * 128; m0 = (by & 7) * 64;
        ntaps = half ? 5 : 4; tbase = half * 4;
        Cout = (void*)((float*)Cout + (long)half * PHALF);
    } else {
        n0 = bx * 128; m0 = by * 64;
        ntaps = Ktot >> ICL2;
    }
    const long RSA = (TMODE == 8) ? 8192 : (long)Ktot * 64;  // A row stride (u16)
    const long RSB2 = (long)RSB * 2;

    int offB[4], ldsOffB[4], ldsOffA[2];
    const char* aBase[2];
    const char* bBase[4];
#pragma unroll
    for (int j = 0; j < 4; ++j) {
        int r = w * 32 + j * 8 + sh;
        int gn = n0 + r;
        if (CMODE == 0)      { gn = min(gn, 3968);  offB[j] = (gn / 63) * 65 + (gn % 63); }
        else if (CMODE == 1) { offB[j] = min(gn, N - 1); }
        else if (CMODE == 2) { gn = min(gn, 16128); offB[j] = (gn / 127) * 510 + (gn % 127) * 2; }
        else                 { gn = min(gn, 3968);  offB[j] = (gn / 63) * 254 + (gn % 63) * 2; }
        ldsOffB[j] = r * 128;
        bBase[j] = (const char*)B + (long)offB[j] * RSB2 + sx * 16;
    }
#pragma unroll
    for (int j = 0; j < 2; ++j) {
        int r = w * 16 + j * 8 + sh;
        ldsOffA[j] = r * 128;
        aBase[j] = (const char*)A + (long)(m0 + r) * RSA * 2 + sx * 16;
    }

    f32x4 acc[2][4];
#pragma unroll
    for (int a = 0; a < 2; ++a)
#pragma unroll
        for (int b = 0; b < 4; ++b) acc[a][b] = (f32x4){0.f, 0.f, 0.f, 0.f};

    for (int t_ = 0; t_ < ntaps; ++t_) {
        int te = t_ + tbase;                 // effective tap
        long tOffB;
        if (TMODE == 8) {
            int trow_;
            if (TW3) { int q_ = (te * 11) >> 5; trow_ = q_ * 65 + (te - q_ * 3); }
            else       trow_ = te * 65;
            tOffB = (long)trow_ * RSB2;
        } else if (TMODE == 4) {
            tOffB = (long)te * 1024;
        } else if (TMODE == 5) {
            int q_ = (te * 11) >> 5;
            tOffB = (long)(q_ * 255 + (te - q_ * 3)) * RSB2;
        } else if (TMODE == 6) {
            int q_ = (te * 11) >> 5;
            tOffB = (long)(q_ * 127 + (te - q_ * 3)) * RSB2;
        } else {
            tOffB = 0;
        }
        long aOff = (long)te * (ICK * 128);
#pragma unroll
        for (int kb = 0; kb < ICK; ++kb) {   // kb*128: compile-time imm
#pragma unroll
            for (int j = 0; j < 2; ++j)
                glds16(aBase[j] + aOff + kb * 128, (char*)As + ldsOffA[j]);
#pragma unroll
            for (int j = 0; j < 4; ++j)
                glds16(bBase[j] + tOffB + kb * 128, (char*)Bs + ldsOffB[j]);
            __syncthreads();                  // vmcnt(0): tile ready
#pragma unroll
            for (int kk = 0; kk < 2; ++kk) {
                bf16x8 af[2], bfr[4];
#pragma unroll
                for (int f = 0; f < 2; ++f) {
                    int rm = wr * 32 + f * 16 + (l & 15);
                    af[f] = *(const bf16x8*)((const char*)As + rm * 128 +
                               (((kk * 4 + (l >> 4)) ^ (rm & 7)) * 16));
                }
#pragma unroll
                for (int f = 0; f < 4; ++f) {
                    int rn = wc * 64 + f * 16 + (l & 15);
                    bfr[f] = *(const bf16x8*)((const char*)Bs + rn * 128 +
                               (((kk * 4 + (l >> 4)) ^ (rn & 7)) * 16));
                }
#pragma unroll
                for (int fm = 0; fm < 2; ++fm)
#pragma unroll
                    for (int fn = 0; fn < 4; ++fn)
                        acc[fm][fn] = __builtin_amdgcn_mfma_f32_16x16x32_bf16(
                            af[fm], bfr[fn], acc[fm][fn], 0, 0, 0);
            }
            __syncthreads();                  // reads done before next STAGE
        }
    }

    // epilogue
#pragma unroll
    for (int fm = 0; fm < 2; ++fm) {
        int gmb = m0 + wr * 32 + fm * 16 + (l >> 4) * 4;
#pragma unroll
        for (int fn = 0; fn < 4; ++fn) {
            int gn = n0 + wc * 64 + fn * 16 + (l & 15);
            f32x4 v = acc[fm][fn];
            if (EMODE == 2) {
                if (gn < N) {
                    int j0 = gmb >> 1;   // even
                    float u0 = 1.f / (1.f + expf(-(v.x + bias0[j0])));
                    float t0 = tanhf(v.y + bias1[j0]);
                    float u1 = 1.f / (1.f + expf(-(v.z + bias0[j0 + 1])));
                    float t1 = tanhf(v.w + bias1[j0 + 1]);
                    float2 o = { u0 * t0 * bias2[j0], u1 * t1 * bias2[j0 + 1] };
                    *(float2*)((float*)Cout + (long)gn * 256 + j0) = o;
                }
            } else if (EMODE == 4) {
                if (gn < N) {
                    float4 bv = *(const float4*)(bias + gmb);
                    u64 pk = (u64)f2bf(v.x + bv.x)
                           | ((u64)f2bf(v.y + bv.y) << 16)
                           | ((u64)f2bf(v.z + bv.z) << 32)
                           | ((u64)f2bf(v.w + bv.w) << 48);
                    *(u64*)((u16*)Cout + (long)gn * M + gmb) = pk;
                }
            } else if (EMODE == 5) {
                if (TMODE == 8 && part >= 0) {
                    // a0 split-K: raw f32 partial, no bias/relu
                    if (gn < 3969) {
                        float4 o = { v.x, v.y, v.z, v.w };
                        *(float4*)(Pbuf + (long)part * PHALF + (long)gn * 512 + gmb) = o;
                    }
                } else if (gn < 3969) {
                    int oy = gn / 63, ox = gn - oy * 63;
                    if (oy < OH && ox < OW) {
                        int trg = obase + oy * OW + ox;
                        float4 bv = *(const float4*)(bias + gmb);
                        u64 pk = (u64)f2bf(fmaxf(v.x + bv.x, 0.f))
                               | ((u64)f2bf(fmaxf(v.y + bv.y, 0.f)) << 16)
                               | ((u64)f2bf(fmaxf(v.z + bv.z, 0.f)) << 32)
                               | ((u64)f2bf(fmaxf(v.w + bv.w, 0.f)) << 48);
                        *(u64*)((u16*)Cout + (long)trg * M + gmb) = pk;
                    }
                }
            } else if (EMODE == 6) {
                if (gn < N) {
                    u64 pk = (u64)f2bf(v.x)
                           | ((u64)f2bf(v.y) << 16)
                           | ((u64)f2bf(v.z) << 32)
                           | ((u64)f2bf(v.w) << 48);
                    *(u64*)((u16*)Cout + (long)gn * M + gmb) = pk;
                }
            } else {   // EMODE 7: f32 partial [gn][512]
                if (gn < 3969) {
                    float4 o = { v.x, v.y, v.z, v.w };
                    *(float4*)((float*)Cout + (long)gn * 512 + gmb) = o;
                }
            }
        }
    }
}

// ---------------- global GEMM wrappers ---------------------------------------
template<int CMODE, int EMODE, int TMODE>
__global__ __launch_bounds__(256) void gemm_k(
    const u16* __restrict__ A, const u16* __restrict__ B,
    const float* __restrict__ bias0, const float* __restrict__ bias1,
    const float* __restrict__ bias2, const float* __restrict__ bias3,
    void* __restrict__ Cout, float* __restrict__ Pbuf,
    int M, int N, int RSB, int Ktot, int OH, int OW, int obase)
{
    __shared__ u16 As[4096];
    __shared__ u16 Bs[8192];
    gemm_body<CMODE, EMODE, TMODE>(blockIdx.x, blockIdx.y, As, Bs, A, B,
                                   bias0, bias1, bias2, bias3, Cout, Pbuf,
                                   M, N, RSB, Ktot, OH, OW, obase);
}

// merged conv1-GEMM (blocks [0,1018)) + Wc-GEMM (blocks [1018,1530))
__global__ __launch_bounds__(256) void conv1_wc_k(
    const u16* __restrict__ Wc1pk, const u16* __restrict__ x_t,
    const float* __restrict__ c1b, u16* __restrict__ h1T,
    const u16* __restrict__ WpkT, const u16* __restrict__ W1pk,
    u16* __restrict__ WcAll)
{
    __shared__ u16 As[4096];
    __shared__ u16 Bs[8192];
    int bid = blockIdx.x;
    if (bid < 1018) {
        gemm_body<1, 4, 9>(bid % 509, bid / 509, As, Bs, Wc1pk, x_t,
                           c1b, nullptr, nullptr, nullptr, h1T, nullptr,
                           128, 65025, 64, 1, 0, 0, 0);
    } else {
        int b2 = bid - 1018;
        gemm_body<1, 6, 4>(b2 & 3, b2 >> 2, As, Bs, WpkT, W1pk,
                           nullptr, nullptr, nullptr, nullptr, WcAll, nullptr,
                           8192, 512, 1024, 16, 0, 0, 0);
    }
}

// ---------------- att[n] = sigmoid(Wab + sum_j UVw[n][j]); also zeros rank --
__global__ __launch_bounds__(256) void att_v3(
    const float* __restrict__ UVw, const float* __restrict__ Wab,
    float* __restrict__ att, int* __restrict__ rank, int N)
{
    int t = threadIdx.x, l = t & 63, r = t >> 6;
    int n = blockIdx.x * 4 + r;
    if (t < 4 && blockIdx.x * 4 + t < N) rank[blockIdx.x * 4 + t] = 0;
    if (n >= N) return;
    float4 p = *(const float4*)(UVw + (long)n * 256 + l * 4);
    float s = (p.x + p.y) + (p.z + p.w);
#pragma unroll
    for (int d = 1; d < 64; d <<= 1) s += __shfl_xor(s, d, 64);
    if (l == 0) att[n] = 1.f / (1.f + expf(-(s + Wab[0])));
}

// ---------------- rank: chunk-parallel partial counts (vectorized) ----------
__global__ __launch_bounds__(256) void rank_partial(
    const float* __restrict__ att, int* __restrict__ rank, int N)
{
    __shared__ float sa[1024];
    int n = blockIdx.x * 256 + threadIdx.x;
    int base = blockIdx.y * 1024;
    int cnt = min(1024, N - base);
    for (int t = threadIdx.x; t < cnt; t += 256) sa[t] = att[base + t];
    __syncthreads();
    if (n >= N) return;
    float a = att[n];
    int r = 0;
    const float4* s4 = (const float4*)sa;
    int gq = cnt >> 2;
    for (int q = 0; q < gq; ++q) {
        float4 v = s4[q];
        r += (int)(v.x > a) + (int)(v.y > a) + (int)(v.z > a) + (int)(v.w > a);
    }
    int bnd = n - base;
    bnd = max(0, min(bnd, cnt));
    int bq = bnd >> 2;
    for (int q = 0; q < bq; ++q) {
        float4 v = s4[q];
        r += (int)(v.x == a) + (int)(v.y == a) + (int)(v.z == a) + (int)(v.w == a);
    }
    for (int t = bq << 2; t < bnd; ++t) r += (int)(sa[t] == a);
    atomicAdd(&rank[n], r);
}

// ---------------- fused tail: fc partials + swpc partials -------------------
#define FC_NB 256
#define FC_ROWS 61   // 256*61 = 15616 >= 15376
__device__ __forceinline__ void anchor_coords(int n, float& cx, float& cy,
                                              float& bw, float& bh)
{
    int kh, kw, Wa, loc;
    if (n < 3721)       { kh = 3; kw = 3; Wa = 61; loc = n; }
    else if (n < 7690)  { kh = 1; kw = 1; Wa = 63; loc = n - 3721; }
    else if (n < 11533) { kh = 3; kw = 1; Wa = 63; loc = n - 7690; }
    else                { kh = 1; kw = 3; Wa = 61; loc = n - 11533; }
    int iy = loc / Wa, ix = loc - iy * Wa;
    cx = (ix + kw * 0.5f) * (1.f / 63.f);
    cy = (iy + kh * 0.5f) * (1.f / 63.f);
    bw = kw * (1.f / 63.f);
    bh = kh * (1.f / 63.f);
}

__global__ __launch_bounds__(256) void tail_part(
    const u16* __restrict__ Hfeat, const float* __restrict__ att,
    const int* __restrict__ rank, float* __restrict__ fcp,
    float* __restrict__ prt, int N)
{
    __shared__ float red[4][50];
    int t = threadIdx.x;
    if (blockIdx.x < FC_NB) {
        int b = blockIdx.x;
        int l = t & 63, r = t >> 6;
        float acc[10][8];
#pragma unroll
        for (int k = 0; k < 10; ++k)
#pragma unroll
            for (int e = 0; e < 8; ++e) acc[k][e] = 0.f;
        int n0 = b * FC_ROWS;
        for (int it = 0; it < 16; ++it) {
            int nl = it * 4 + r;
            int n = n0 + nl;
            if (nl >= FC_ROWS || n >= N) break;   // wave-uniform exit
            float a = att[n];
            int c = (rank[n] * 10) / N;
            bf16x8 h8 = *(const bf16x8*)(Hfeat + (long)n * 512 + l * 8);
            float hf[8];
#pragma unroll
            for (int e = 0; e < 8; ++e) hf[e] = bf2f((u16)h8[e]);
#pragma unroll
            for (int k = 0; k < 10; ++k) {
                float sel = (c == k) ? a : 0.f;
#pragma unroll
                for (int e = 0; e < 8; ++e)
                    acc[k][e] = fmaf(sel, hf[e], acc[k][e]);
            }
        }
        float* dst = fcp + (long)b * 5120 + l * 8;
#pragma unroll
        for (int k = 0; k < 10; ++k)
#pragma unroll
            for (int e = 0; e < 8; ++e) dst[k * 512 + e] = acc[k][e];
    } else {
        int b = blockIdx.x - FC_NB;
        int n = b * 256 + t;
        int l = t & 63, w = t >> 6;
        float a = 0.f, cx = 0.f, cy = 0.f, bw = 0.f, bh = 0.f;
        int c = -1;
        if (n < N) {
            a = att[n]; c = (rank[n] * 10) / N;
            anchor_coords(n, cx, cy, bw, bh);
        }
#pragma unroll
        for (int k = 0; k < 10; ++k) {
            float sel = (c == k) ? a : 0.f;
            float v[5] = {sel, sel * cx, sel * cy, sel * bw, sel * bh};
#pragma unroll
            for (int d = 0; d < 5; ++d) {
                float x = v[d];
#pragma unroll
                for (int s = 1; s < 64; s <<= 1) x += __shfl_xor(x, s, 64);
                if (l == 0) red[w][k * 5 + d] = x;
            }
        }
        __syncthreads();
        if (t < 50) prt[b * 50 + t] = red[0][t] + red[1][t] + red[2][t] + red[3][t];
    }
}

// fc_raw[i] = sum_b fcp[b][i], fixed order (deterministic, coalesced)
__global__ __launch_bounds__(256) void fc_sum(
    const float* __restrict__ fcp, float* __restrict__ fc_raw)
{
    int i = blockIdx.x * 256 + threadIdx.x;
    if (i >= 5120) return;
    float s = 0.f;
    for (int b = 0; b < FC_NB; ++b) s += fcp[(long)b * 5120 + i];
    fc_raw[i] = s;
}

// ---------------- head (includes swpc final sum) ----------------------------
__global__ __launch_bounds__(512) void final_kernel(
    const float* __restrict__ fc_raw, const float* __restrict__ prt,
    const float* __restrict__ cluster_w, const float* __restrict__ cluster_b,
    const float* __restrict__ cls_w, const float* __restrict__ cls_b,
    float* __restrict__ out)
{
    __shared__ float red[512];
    __shared__ float swpc[50];   // k*5+d: d=0 sw, d=1..4 pc
    int t = threadIdx.x;
    if (t < 50) {
        float s = 0.f;
        for (int b = 0; b < 61; ++b) s += prt[b * 50 + t];
        swpc[t] = s;
    }
    __syncthreads();
    float fcn[10];
#pragma unroll
    for (int k = 0; k < 10; ++k)
        fcn[k] = fc_raw[k * 512 + t] / (swpc[k * 5] + 1e-8f);
    float cw = cluster_w[t];
    float sc[10];
#pragma unroll
    for (int k = 0; k < 10; ++k) {
        red[t] = fcn[k] * cw;
        __syncthreads();
        for (int s = 256; s > 0; s >>= 1) {
            if (t < s) red[t] += red[t + s];
            __syncthreads();
        }
        sc[k] = red[0] + cluster_b[0];
        __syncthreads();
    }
    float mx = sc[0];
#pragma unroll
    for (int k = 1; k < 10; ++k) mx = fmaxf(mx, sc[k]);
    float se = 0.f;
#pragma unroll
    for (int k = 0; k < 10; ++k) { sc[k] = expf(sc[k] - mx); se += sc[k]; }
    float inv = 1.f / se;
#pragma unroll
    for (int k = 0; k < 10; ++k) sc[k] *= inv;
    float fm = 0.f;
#pragma unroll
    for (int k = 0; k < 10; ++k) fm = fmaf(sc[k], fcn[k], fm);
    float lg[10];
#pragma unroll
    for (int c = 0; c < 10; ++c) {
        red[t] = fm * cls_w[c * 512 + t];
        __syncthreads();
        for (int s = 256; s > 0; s >>= 1) {
            if (t < s) red[t] += red[t + s];
            __syncthreads();
        }
        lg[c] = red[0] + cls_b[c];
        __syncthreads();
    }
    float mx2 = lg[0];
#pragma unroll
    for (int c = 1; c < 10; ++c) mx2 = fmaxf(mx2, lg[c]);
    float se2 = 0.f;
#pragma unroll
    for (int c = 0; c < 10; ++c) { lg[c] = expf(lg[c] - mx2); se2 += lg[c]; }
    float inv2 = 1.f / se2;
    if (t < 10) out[t] = lg[t] * inv2;
    if (t >= 10 && t < 20) out[t] = sc[t - 10];
    if (t >= 20 && t < 60) {
        int i = t - 20;
        int k = i >> 2, d = i & 3;
        out[t] = swpc[k * 5 + 1 + d] / (swpc[k * 5] + 1e-8f);
    }
}

// ---------------------------------------------------------------------------
extern "C" void kernel_launch(void* const* d_in, const int* in_sizes, int n_in,
                              void* d_out, int out_size, void* d_ws, size_t ws_size,
                              hipStream_t stream)
{
    const float* x    = (const float*)d_in[0];
    const float* c1w  = (const float*)d_in[1];   const float* c1b = (const float*)d_in[2];
    const float* c2w  = (const float*)d_in[3];   const float* c2b = (const float*)d_in[4];
    const float* c3w  = (const float*)d_in[5];   const float* c3b = (const float*)d_in[6];
    const float* a0w  = (const float*)d_in[7];   const float* a0b = (const float*)d_in[8];
    const float* a1w  = (const float*)d_in[9];   const float* a1b = (const float*)d_in[10];
    const float* a2w  = (const float*)d_in[11];  const float* a2b = (const float*)d_in[12];
    const float* a3w  = (const float*)d_in[13];  const float* a3b = (const float*)d_in[14];
    const float* W1w  = (const float*)d_in[15];  const float* W1b = (const float*)d_in[16];
    const float* Uw   = (const float*)d_in[17];  const float* Ub  = (const float*)d_in[18];
    const float* Vw   = (const float*)d_in[19];  const float* Vb  = (const float*)d_in[20];
    const float* Waw  = (const float*)d_in[21];  const float* Wab = (const float*)d_in[22];
    const float* clw  = (const float*)d_in[23];  const float* clb = (const float*)d_in[24];
    const float* clsw = (const float*)d_in[25];  const float* clsb= (const float*)d_in[26];
    float* out = (float*)d_out;

    // ---- workspace layout (float units) -----------------------------------
    float* ws = (float*)d_ws;
    u16*   Hfeat= (u16*)ws;                     // 15376*512 u16    @0
    u16*   h1T  = (u16*)(ws + 3936256);         // 65025*128 u16
    u16*   h2T  = (u16*)(ws + 8097856);         // 16129*256 u16
    u16*   h3T  = (u16*)(ws + 10162368);        // 4225*512 u16
    float* UVw  = ws + 11243968;                // 15376*256 f32
    u16*   x_t  = (u16*)(ws + 11243968);        //   65025*64 u16 (overlay, dead b4 UVw)
    u16*   Wpk  = (u16*)(ws + 15180224);        // W1pk/Wc2pk/Wc3pk
    float* P    = ws + 15180224;                //   split-K partials 2*PHALF (overlay;
                                                //   [15.18M,19.24M) < W1pk 19.37M)
    u16*   WpkT = (u16*)(ws + 20505024);        // 8192*1024 u16 (dead after Wc GEMM)
    u16*   WcAll= (u16*)(ws + 24699328);        // 512*8192 u16
    float* hb   = ws + 26796480;                // 2048
    float* att  = ws + 26798528;                // 15,376
    int*   rank = (int*)(ws + 26813904);        // 15,376
    float* fcr  = ws + 26829280;                // 5,120
    float* fcp  = ws + 26834400;                // 256*5120
    float* prt  = ws + 28145120;                // 61*50
    u16*   Wc1pk= (u16*)(ws + 28148224);        // 128*64 u16
    u16*   UVpk = (u16*)(ws + 28152320);        // 512*512 u16 (dedicated, safe)
    // total ~28.29M floats ~= 113.2 MB

    u16* W1pk  = Wpk + 8388608;
    u16* Wc2pk = Wpk + 9175040;
    u16* Wc3pk = Wpk + 9469952;

    dim3 blk(256);
    const float* nul = nullptr;
    float* fnul = nullptr;

    // ---- prep (input-only deps; includes anchor packT) ---------------------
    prep_all<<<dim3(11679), blk, 0, stream>>>(W1w, Uw, Vw, c2w, c3w, Wpk, UVpk,
                                              c1w, Wc1pk, x, x_t, W1w, W1b,
                                              a0b, a1b, a2b, a3b, hb,
                                              a0w, a1w, a2w, a3w, WpkT);

    // ---- conv1 GEMM + Wc GEMM, one dispatch (independent) ------------------
    conv1_wc_k<<<dim3(1530), blk, 0, stream>>>(Wc1pk, x_t, c1b, h1T,
                                               WpkT, W1pk, WcAll);

    // ---- backbone ----------------------------------------------------------
    gemm_k<2,4,5><<<dim3(127, 4), blk, 0, stream>>>(Wc2pk, h1T, c2b, nul, nul, nul, h2T, fnul, 256, 16129, 128, 18, 0, 0, 0);
    gemm_k<3,7,6><<<dim3(32, 16), blk, 0, stream>>>(Wc3pk, h2T, nul, nul, nul, nul, P, fnul, 512, 3969, 256, 36, 0, 0, 0);
    comb3<<<dim3(3969), blk, 0, stream>>>(P, c3b, h3T);

    // ---- fused anchor+W1 GEMMs (job table, a0 2-way split-K, XCD swizzle) --
    gemm_k<0,5,8><<<dim3(1280), blk, 0, stream>>>(WcAll, h3T, hb, nul, nul, nul, Hfeat, P, 512, 3969, 512, 0, 0, 0, 0);
    combA<<<dim3(3721), blk, 0, stream>>>(P, hb, Hfeat);

    // ---- UV GEMM: UVw[n][256] = Wa[j]*sigmoid(u_j)*tanh(v_j), f32 ----------
    gemm_k<1,2,1><<<dim3(121, 8), blk, 0, stream>>>(UVpk, Hfeat, Ub, Vb, Waw, nul, UVw, fnul, 512, NTOT, 512, 8, 0, 0, 0);

    // ---- attention (+rank zero), rank, reductions, head --------------------
    att_v3<<<dim3(3844), blk, 0, stream>>>(UVw, Wab, att, rank, NTOT);
    rank_partial<<<dim3(61, 16), blk, 0, stream>>>(att, rank, NTOT);
    tail_part<<<dim3(FC_NB + 61), blk, 0, stream>>>(Hfeat, att, rank, fcp, prt, NTOT);
    fc_sum<<<dim3(20), blk, 0, stream>>>(fcp, fcr);
    final_kernel<<<dim3(1), dim3(512), 0, stream>>>(fcr, prt, clw, clb, clsw, clsb, out);
}